// Round 4
// baseline (1826.791 us; speedup 1.0000x reference)
//
#include <hip/hip_runtime.h>
#include <hip/hip_bf16.h>

// ARMANet: 2x ARMAConv(K=1,T=1) + global mean pool + FC
// N=100000 nodes, E=1600000 edges, IN=HID=64, OUT=32, G=64 graphs.
// R4: R3 (bucketed edges + LDS-accumulated propagate) with the final_fc
//     grid bug fixed (needs 8 blocks for 2048 outputs, not 1).

#define NB 256          // destination nodes per bucket
#define CAP 5120        // edge capacity per bucket (mean 4092, sigma ~64)
#define MAXB 400        // max buckets (N=100000 -> 391)
#define P1_CHUNK 4096   // edges per bucket_kernel block
#define POOL_CHUNK 1024

typedef unsigned long long ull;

// ---------------- bucket edges by destination (block-local multi-split) ----------------
__global__ __launch_bounds__(256) void bucket_kernel(
    const int* __restrict__ row, const int* __restrict__ col,
    ull* __restrict__ bpack, int* __restrict__ bcnt, int E) {
    __shared__ int hist[MAXB];
    __shared__ int ofs[MAXB];
    __shared__ int cur[MAXB];
    __shared__ int gbase[MAXB];
    __shared__ int s[256];
    __shared__ ull stage[P1_CHUNK];

    int t = threadIdx.x;
    for (int i = t; i < MAXB; i += 256) hist[i] = 0;
    __syncthreads();

    int e0 = blockIdx.x * P1_CHUNK;
    int cntE = min(E - e0, P1_CHUNK);

    // ph1: histogram
    for (int i = t; i < cntE; i += 256) {
        int c = col[e0 + i];
        atomicAdd(&hist[c >> 8], 1);
    }
    __syncthreads();

    // ph2: exclusive scan of hist (2 elems per thread + Hillis-Steele on 256 partials)
    int i2 = 2 * t;
    int a = (i2 < MAXB) ? hist[i2] : 0;
    int b = (i2 + 1 < MAXB) ? hist[i2 + 1] : 0;
    s[t] = a + b;
    __syncthreads();
    for (int off = 1; off < 256; off <<= 1) {
        int x = (t >= off) ? s[t - off] : 0;
        __syncthreads();
        s[t] += x;
        __syncthreads();
    }
    int excl = (t > 0) ? s[t - 1] : 0;
    if (i2 < MAXB) ofs[i2] = excl;
    if (i2 + 1 < MAXB) ofs[i2 + 1] = excl + a;
    __syncthreads();

    // init cursors + reserve global space (one atomic per non-empty bucket)
    for (int i = t; i < MAXB; i += 256) {
        cur[i] = ofs[i];
        gbase[i] = hist[i] ? atomicAdd(&bcnt[i], hist[i]) : 0;
    }
    __syncthreads();

    // ph3: stage edges grouped by bucket in LDS
    for (int i = t; i < cntE; i += 256) {
        int c = col[e0 + i];
        int r = row[e0 + i];
        int bk = c >> 8;
        int k = atomicAdd(&cur[bk], 1);
        stage[k] = ((ull)(unsigned)c << 32) | (unsigned)r;
    }
    __syncthreads();

    // ph4: contiguous per-bucket runs -> global
    for (int i = t; i < cntE; i += 256) {
        ull pk = stage[i];
        int c = (int)(pk >> 32);
        int bk = c >> 8;
        int gd = gbase[bk] + (i - ofs[bk]);
        if (gd < CAP) bpack[(size_t)bk * CAP + gd] = pk;
    }
}

// ---------------- per-bucket in-degree -> dinv (no global atomics) ----------------
__global__ __launch_bounds__(256) void dinv_bucket(
    const ull* __restrict__ bpack, const int* __restrict__ bcnt,
    float* __restrict__ dinv, int n) {
    __shared__ int h[NB];
    int b = blockIdx.x, t = threadIdx.x;
    h[t] = 0;
    __syncthreads();
    int cnt = min(bcnt[b], CAP);
    size_t base = (size_t)b * CAP;
    for (int i = t; i < cnt; i += 256) {
        int c = (int)(bpack[base + i] >> 32);
        atomicAdd(&h[c & (NB - 1)], 1);
    }
    __syncthreads();
    int node = b * NB + t;
    if (node < n) dinv[node] = h[t] ? rsqrtf((float)h[t]) : 0.0f;
}

// ---------------- per-edge norm weights ----------------
__global__ __launch_bounds__(256) void wnorm_kernel(
    const ull* __restrict__ bpack, const int* __restrict__ bcnt,
    const float* __restrict__ dinv, float* __restrict__ bw) {
    int b = blockIdx.x;
    int cnt = min(bcnt[b], CAP);
    size_t base = (size_t)b * CAP;
    for (int i = threadIdx.x; i < cnt; i += 256) {
        ull pk = bpack[base + i];
        int c = (int)(pk >> 32);
        int r = (int)pk;
        bw[base + i] = dinv[r] * dinv[c];
    }
}

// ---------------- dual GEMM: T = X@W1, R = X@W2 + b (weights in registers) ----------------
__global__ __launch_bounds__(256) void gemm_dual(
    const float* __restrict__ X, const float* __restrict__ W1,
    const float* __restrict__ W2, const float* __restrict__ bias,
    float* __restrict__ T, float* __restrict__ R, int n) {
    __shared__ float sX[64 * 64];
    int t = threadIdx.x;
    int d = t & 63;
    int i0 = t >> 6;

    float w1r[64], w2r[64];
#pragma unroll
    for (int k = 0; k < 64; ++k) {
        w1r[k] = W1[k * 64 + d];
        w2r[k] = W2[k * 64 + d];
    }

    int node0 = blockIdx.x * 64;
    for (int i = t * 4; i < 4096; i += 1024) {
        int rr = i >> 6, cc = i & 63;
        int node = node0 + rr;
        float4 v = make_float4(0.f, 0.f, 0.f, 0.f);
        if (node < n) v = *(const float4*)&X[(size_t)node * 64 + cc];
        *(float4*)&sX[i] = v;
    }
    __syncthreads();

    float bi = bias[d];
    for (int i = i0; i < 64; i += 4) {
        int node = node0 + i;
        if (node >= n) break;
        float a1 = 0.f, a2 = 0.f;
#pragma unroll
        for (int k4 = 0; k4 < 16; ++k4) {
            float4 xv = *(const float4*)&sX[i * 64 + k4 * 4];
            a1 = fmaf(xv.x, w1r[k4 * 4 + 0], a1);
            a2 = fmaf(xv.x, w2r[k4 * 4 + 0], a2);
            a1 = fmaf(xv.y, w1r[k4 * 4 + 1], a1);
            a2 = fmaf(xv.y, w2r[k4 * 4 + 1], a2);
            a1 = fmaf(xv.z, w1r[k4 * 4 + 2], a1);
            a2 = fmaf(xv.z, w2r[k4 * 4 + 2], a2);
            a1 = fmaf(xv.w, w1r[k4 * 4 + 3], a1);
            a2 = fmaf(xv.w, w2r[k4 * 4 + 3], a2);
        }
        T[(size_t)node * 64 + d] = a1;
        R[(size_t)node * 64 + d] = a2 + bi;
    }
}

// ---------------- bucketed propagate + fused relu ----------------
// H[c,:] = relu( sum_{e: col=c} w_e * T[row_e,:] + R[c,:] ), H may alias R.
__global__ __launch_bounds__(256) void prop_kernel(
    const float* __restrict__ T, const float* __restrict__ R,
    const ull* __restrict__ bpack, const float* __restrict__ bw,
    const int* __restrict__ bcnt, float* __restrict__ H, int n) {
    __shared__ float AGG[NB * 64];  // 64 KB
    int t = threadIdx.x;
    for (int i = t * 4; i < NB * 64; i += 1024) {
        *(float4*)&AGG[i] = make_float4(0.f, 0.f, 0.f, 0.f);
    }
    __syncthreads();

    int b = blockIdx.x;
    int cnt = min(bcnt[b], CAP);
    size_t base = (size_t)b * CAP;
    int w = t >> 6, d = t & 63;

    for (int ebase = w * 64; ebase < cnt; ebase += 256) {
        int m = min(cnt - ebase, 64);
        ull pk = 0;
        float wt = 0.f;
        if (d < m) {
            pk = bpack[base + ebase + d];
            wt = bw[base + ebase + d];
        }
        int j = 0;
        for (; j + 4 <= m; j += 4) {
            ull p0 = __shfl(pk, j), p1 = __shfl(pk, j + 1);
            ull p2 = __shfl(pk, j + 2), p3 = __shfl(pk, j + 3);
            float w0 = __shfl(wt, j), w1 = __shfl(wt, j + 1);
            float w2 = __shfl(wt, j + 2), w3 = __shfl(wt, j + 3);
            int r0 = (int)p0, r1 = (int)p1, r2 = (int)p2, r3 = (int)p3;
            int cl0 = ((int)(p0 >> 32)) & (NB - 1);
            int cl1 = ((int)(p1 >> 32)) & (NB - 1);
            int cl2 = ((int)(p2 >> 32)) & (NB - 1);
            int cl3 = ((int)(p3 >> 32)) & (NB - 1);
            float v0 = T[(size_t)r0 * 64 + d] * w0;
            float v1 = T[(size_t)r1 * 64 + d] * w1;
            float v2 = T[(size_t)r2 * 64 + d] * w2;
            float v3 = T[(size_t)r3 * 64 + d] * w3;
            atomicAdd(&AGG[cl0 * 64 + d], v0);
            atomicAdd(&AGG[cl1 * 64 + d], v1);
            atomicAdd(&AGG[cl2 * 64 + d], v2);
            atomicAdd(&AGG[cl3 * 64 + d], v3);
        }
        for (; j < m; ++j) {
            ull p0 = __shfl(pk, j);
            float w0 = __shfl(wt, j);
            int r0 = (int)p0;
            int cl0 = ((int)(p0 >> 32)) & (NB - 1);
            float v0 = T[(size_t)r0 * 64 + d] * w0;
            atomicAdd(&AGG[cl0 * 64 + d], v0);
        }
    }
    __syncthreads();

    int c0 = b * NB;
    for (int i = w; i < NB; i += 4) {
        int c = c0 + i;
        if (c < n) {
            float hv = AGG[i * 64 + d] + R[(size_t)c * 64 + d];
            H[(size_t)c * 64 + d] = fmaxf(hv, 0.0f);
        }
    }
}

// ---------------- pooled[batch] += h ; cnt[batch] += 1 ----------------
__global__ __launch_bounds__(256) void pool_kernel(
    const float* __restrict__ Hin, const int* __restrict__ batch,
    float* __restrict__ pooled, float* __restrict__ cnt, int n) {
    __shared__ float sAcc[64 * 64];
    __shared__ float sCnt[64];
    int tid = threadIdx.x;
    for (int i = tid; i < 4096; i += 256) sAcc[i] = 0.0f;
    if (tid < 64) sCnt[tid] = 0.0f;
    __syncthreads();
    int s = blockIdx.x * POOL_CHUNK;
    int e = min(s + POOL_CHUNK, n);
    int d = tid & 63;
    int i0 = tid >> 6;
    for (int i = s + i0; i < e; i += 4) {
        float v = Hin[(size_t)i * 64 + d];
        int g = batch[i];
        atomicAdd(&sAcc[g * 64 + d], v);
        if (d == 0) atomicAdd(&sCnt[g], 1.0f);
    }
    __syncthreads();
    for (int i = tid; i < 4096; i += 256) {
        float v = sAcc[i];
        if (v != 0.0f) atomicAdd(&pooled[i], v);
    }
    if (tid < 64) {
        float v = sCnt[tid];
        if (v != 0.0f) atomicAdd(&cnt[tid], v);
    }
}

// ---------------- out[g,o] = (pooled[g,:]/max(cnt,1)) @ fcw + fcb ----------------
__global__ void final_fc(const float* __restrict__ pooled, const float* __restrict__ cnt,
                         const float* __restrict__ fcw, const float* __restrict__ fcb,
                         float* __restrict__ out) {
    int idx = blockIdx.x * 256 + threadIdx.x;
    if (idx >= 64 * 32) return;
    int g = idx >> 5, o = idx & 31;
    float c = fmaxf(cnt[g], 1.0f);
    float acc = 0.0f;
#pragma unroll
    for (int k = 0; k < 64; ++k) acc = fmaf(pooled[g * 64 + k], fcw[k * 32 + o], acc);
    out[idx] = acc / c + fcb[o];
}

extern "C" void kernel_launch(void* const* d_in, const int* in_sizes, int n_in,
                              void* d_out, int out_size, void* d_ws, size_t ws_size,
                              hipStream_t stream) {
    const float* x       = (const float*)d_in[0];
    const int*   eidx    = (const int*)d_in[1];
    const int*   batch   = (const int*)d_in[2];
    const float* w1_init = (const float*)d_in[3];
    const float* w1_root = (const float*)d_in[4];
    const float* b1      = (const float*)d_in[5];
    const float* w2_init = (const float*)d_in[6];
    const float* w2_root = (const float*)d_in[7];
    const float* b2      = (const float*)d_in[8];
    const float* fc_w    = (const float*)d_in[9];
    const float* fc_b    = (const float*)d_in[10];
    float* out = (float*)d_out;

    const int N = in_sizes[0] / 64;
    const int E = in_sizes[1] / 2;
    const int* row = eidx;
    const int* col = eidx + E;

    const int B = (N + NB - 1) / NB;  // 391 buckets

    // workspace layout (ws 8B-aligned): bpack | bw | bcnt | dinv | pooled | cnt | bufA | bufB
    ull*   bpack  = (ull*)d_ws;                       // B*CAP
    float* bw     = (float*)(bpack + (size_t)B * CAP);// B*CAP
    int*   bcnt   = (int*)(bw + (size_t)B * CAP);     // B
    float* dinv   = (float*)(bcnt + B);               // N
    float* pooled = dinv + N;                         // 4096
    float* cnt    = pooled + 64 * 64;                 // 64
    float* bufA   = cnt + 64;                         // N*64
    float* bufB   = bufA + (size_t)N * 64;            // N*64

    hipMemsetAsync(bcnt, 0, (size_t)B * sizeof(int), stream);
    hipMemsetAsync(pooled, 0, (size_t)(64 * 64 + 64) * sizeof(float), stream);

    // bucket edges, degrees, per-edge weights (shared by both layers)
    bucket_kernel<<<(E + P1_CHUNK - 1) / P1_CHUNK, 256, 0, stream>>>(row, col, bpack, bcnt, E);
    dinv_bucket<<<B, 256, 0, stream>>>(bpack, bcnt, dinv, N);
    wnorm_kernel<<<B, 256, 0, stream>>>(bpack, bcnt, dinv, bw);

    // layer 1
    gemm_dual<<<(N + 63) / 64, 256, 0, stream>>>(x, w1_init, w1_root, b1, bufA, bufB, N);
    prop_kernel<<<B, 256, 0, stream>>>(bufA, bufB, bpack, bw, bcnt, bufB, N);

    // layer 2
    gemm_dual<<<(N + 63) / 64, 256, 0, stream>>>(bufB, w2_init, w2_root, b2, bufA, bufB, N);
    prop_kernel<<<B, 256, 0, stream>>>(bufA, bufB, bpack, bw, bcnt, bufB, N);

    // pool + FC
    pool_kernel<<<(N + POOL_CHUNK - 1) / POOL_CHUNK, 256, 0, stream>>>(bufB, batch, pooled, cnt, N);
    final_fc<<<(64 * 32 + 255) / 256, 256, 0, stream>>>(pooled, cnt, fc_w, fc_b, out);
}

// Round 5
// 461.096 us; speedup vs baseline: 3.9618x; 3.9618x over previous
//
#include <hip/hip_runtime.h>
#include <hip/hip_bf16.h>

// ARMANet: 2x ARMAConv(K=1,T=1) + global mean pool + FC
// N=100000 nodes, E=1600000 edges, IN=HID=64, OUT=32, G=64 graphs.
// R5: bucket (contiguous writes) -> per-bucket counting sort to full CSR
//     (no global atomics, L2-local scatter) -> full-occupancy per-node
//     register gather with fused relu. No 64KB-LDS accumulator kernels.

#define NB 256          // destination nodes per bucket
#define CAP 5120        // edge capacity per bucket (mean 4092, sigma ~64)
#define MAXB 400        // max buckets (N=100000 -> 391)
#define P1_CHUNK 4096   // edges per bucket_kernel block
#define POOL_CHUNK 1024

typedef unsigned long long ull;

// ---------------- stage 1: bucket edges by destination (block-local multi-split) ----------------
__global__ __launch_bounds__(256) void bucket_kernel(
    const int* __restrict__ row, const int* __restrict__ col,
    ull* __restrict__ bpack, int* __restrict__ bcnt, int E) {
    __shared__ int hist[MAXB];
    __shared__ int ofs[MAXB];
    __shared__ int cur[MAXB];
    __shared__ int gbase[MAXB];
    __shared__ int s[256];
    __shared__ ull stage[P1_CHUNK];

    int t = threadIdx.x;
    for (int i = t; i < MAXB; i += 256) hist[i] = 0;
    __syncthreads();

    int e0 = blockIdx.x * P1_CHUNK;
    int cntE = min(E - e0, P1_CHUNK);

    // ph1: histogram over destination buckets
    for (int i = t; i < cntE; i += 256) {
        int c = col[e0 + i];
        atomicAdd(&hist[c >> 8], 1);
    }
    __syncthreads();

    // ph2: exclusive scan of hist
    int i2 = 2 * t;
    int a = (i2 < MAXB) ? hist[i2] : 0;
    int b = (i2 + 1 < MAXB) ? hist[i2 + 1] : 0;
    s[t] = a + b;
    __syncthreads();
    for (int off = 1; off < 256; off <<= 1) {
        int x = (t >= off) ? s[t - off] : 0;
        __syncthreads();
        s[t] += x;
        __syncthreads();
    }
    int excl = (t > 0) ? s[t - 1] : 0;
    if (i2 < MAXB) ofs[i2] = excl;
    if (i2 + 1 < MAXB) ofs[i2 + 1] = excl + a;
    __syncthreads();

    // reserve global space: one atomic per non-empty bucket per block
    for (int i = t; i < MAXB; i += 256) {
        cur[i] = ofs[i];
        gbase[i] = hist[i] ? atomicAdd(&bcnt[i], hist[i]) : 0;
    }
    __syncthreads();

    // ph3: stage edges grouped by bucket in LDS
    for (int i = t; i < cntE; i += 256) {
        int c = col[e0 + i];
        int r = row[e0 + i];
        int bk = c >> 8;
        int k = atomicAdd(&cur[bk], 1);
        stage[k] = ((ull)(unsigned)c << 32) | (unsigned)r;
    }
    __syncthreads();

    // ph4: contiguous per-bucket runs -> global
    for (int i = t; i < cntE; i += 256) {
        ull pk = stage[i];
        int c = (int)(pk >> 32);
        int bk = c >> 8;
        int gd = gbase[bk] + (i - ofs[bk]);
        if (gd < CAP) bpack[(size_t)bk * CAP + gd] = pk;
    }
}

// ---------------- stage 2: per-bucket counting sort -> CSR + dinv ----------------
__global__ __launch_bounds__(256) void csr_kernel(
    const ull* __restrict__ bpack, const int* __restrict__ bcnt,
    int* __restrict__ es, int* __restrict__ nstart, int* __restrict__ ndeg,
    float* __restrict__ dinv, int n) {
    __shared__ int h[NB];
    __shared__ int s[NB];
    __shared__ int cur[NB];
    int b = blockIdx.x, t = threadIdx.x;
    h[t] = 0;
    __syncthreads();
    int cnt = min(bcnt[b], CAP);
    size_t base = (size_t)b * CAP;
    for (int i = t; i < cnt; i += 256) {
        int c = (int)(bpack[base + i] >> 32);
        atomicAdd(&h[c & (NB - 1)], 1);
    }
    __syncthreads();
    s[t] = h[t];
    __syncthreads();
    for (int off = 1; off < 256; off <<= 1) {
        int x = (t >= off) ? s[t - off] : 0;
        __syncthreads();
        s[t] += x;
        __syncthreads();
    }
    int myofs = s[t] - h[t];  // exclusive
    cur[t] = myofs;
    int node = b * NB + t;
    if (node < n) {
        nstart[node] = (int)base + myofs;
        ndeg[node] = h[t];
        dinv[node] = h[t] ? rsqrtf((float)h[t]) : 0.0f;
    }
    __syncthreads();
    // scatter src ids into this bucket's 20KB window (L2-local)
    for (int i = t; i < cnt; i += 256) {
        ull pk = bpack[base + i];
        int cl = ((int)(pk >> 32)) & (NB - 1);
        int p = atomicAdd(&cur[cl], 1);
        es[base + p] = (int)pk;
    }
}

// ---------------- dual GEMM: T = X@W1, R = X@W2 + b (weights in registers) ----------------
__global__ __launch_bounds__(256) void gemm_dual(
    const float* __restrict__ X, const float* __restrict__ W1,
    const float* __restrict__ W2, const float* __restrict__ bias,
    float* __restrict__ T, float* __restrict__ R, int n) {
    __shared__ float sX[64 * 64];
    int t = threadIdx.x;
    int d = t & 63;
    int i0 = t >> 6;

    float w1r[64], w2r[64];
#pragma unroll
    for (int k = 0; k < 64; ++k) {
        w1r[k] = W1[k * 64 + d];
        w2r[k] = W2[k * 64 + d];
    }

    int node0 = blockIdx.x * 64;
    for (int i = t * 4; i < 4096; i += 1024) {
        int rr = i >> 6, cc = i & 63;
        int node = node0 + rr;
        float4 v = make_float4(0.f, 0.f, 0.f, 0.f);
        if (node < n) v = *(const float4*)&X[(size_t)node * 64 + cc];
        *(float4*)&sX[i] = v;
    }
    __syncthreads();

    float bi = bias[d];
    for (int i = i0; i < 64; i += 4) {
        int node = node0 + i;
        if (node >= n) break;
        float a1 = 0.f, a2 = 0.f;
#pragma unroll
        for (int k4 = 0; k4 < 16; ++k4) {
            float4 xv = *(const float4*)&sX[i * 64 + k4 * 4];
            a1 = fmaf(xv.x, w1r[k4 * 4 + 0], a1);
            a2 = fmaf(xv.x, w2r[k4 * 4 + 0], a2);
            a1 = fmaf(xv.y, w1r[k4 * 4 + 1], a1);
            a2 = fmaf(xv.y, w2r[k4 * 4 + 1], a2);
            a1 = fmaf(xv.z, w1r[k4 * 4 + 2], a1);
            a2 = fmaf(xv.z, w2r[k4 * 4 + 2], a2);
            a1 = fmaf(xv.w, w1r[k4 * 4 + 3], a1);
            a2 = fmaf(xv.w, w2r[k4 * 4 + 3], a2);
        }
        T[(size_t)node * 64 + d] = a1;
        R[(size_t)node * 64 + d] = a2 + bi;
    }
}

// ---------------- fused gather-propagate + relu (one wave per dst node) ----------------
// H[c,:] = relu( sum_{e in CSR(c)} dinv[src]*dinv[c] * T[src,:] + R[c,:] ), H may alias R.
__global__ __launch_bounds__(256) void gather_fused(
    const float* __restrict__ T, const float* __restrict__ R,
    const int* __restrict__ es, const int* __restrict__ nstart,
    const int* __restrict__ ndeg, const float* __restrict__ dinv,
    float* __restrict__ H, int n) {
    int c = blockIdx.x * 4 + (threadIdx.x >> 6);
    if (c >= n) return;
    int d = threadIdx.x & 63;
    int deg = ndeg[c];
    int s0 = nstart[c];
    float dc = dinv[c];
    float acc = 0.0f;
    for (int base = 0; base < deg; base += 64) {
        int m = min(deg - base, 64);
        int sid = 0;
        float w = 0.0f;
        if (d < m) {
            sid = es[s0 + base + d];
            w = dinv[sid] * dc;
        }
        int j = 0;
        for (; j + 4 <= m; j += 4) {
            int r0 = __shfl(sid, j), r1 = __shfl(sid, j + 1);
            int r2 = __shfl(sid, j + 2), r3 = __shfl(sid, j + 3);
            float w0 = __shfl(w, j), w1 = __shfl(w, j + 1);
            float w2 = __shfl(w, j + 2), w3 = __shfl(w, j + 3);
            float t0 = T[(size_t)r0 * 64 + d];
            float t1 = T[(size_t)r1 * 64 + d];
            float t2 = T[(size_t)r2 * 64 + d];
            float t3 = T[(size_t)r3 * 64 + d];
            acc = fmaf(w0, t0, acc);
            acc = fmaf(w1, t1, acc);
            acc = fmaf(w2, t2, acc);
            acc = fmaf(w3, t3, acc);
        }
        for (; j < m; ++j) {
            int r0 = __shfl(sid, j);
            float w0 = __shfl(w, j);
            acc = fmaf(w0, T[(size_t)r0 * 64 + d], acc);
        }
    }
    float hv = acc + R[(size_t)c * 64 + d];
    H[(size_t)c * 64 + d] = fmaxf(hv, 0.0f);
}

// ---------------- pooled[batch] += h ; cnt[batch] += 1 ----------------
__global__ __launch_bounds__(256) void pool_kernel(
    const float* __restrict__ Hin, const int* __restrict__ batch,
    float* __restrict__ pooled, float* __restrict__ cnt, int n) {
    __shared__ float sAcc[64 * 64];
    __shared__ float sCnt[64];
    int tid = threadIdx.x;
    for (int i = tid; i < 4096; i += 256) sAcc[i] = 0.0f;
    if (tid < 64) sCnt[tid] = 0.0f;
    __syncthreads();
    int s = blockIdx.x * POOL_CHUNK;
    int e = min(s + POOL_CHUNK, n);
    int d = tid & 63;
    int i0 = tid >> 6;
    for (int i = s + i0; i < e; i += 4) {
        float v = Hin[(size_t)i * 64 + d];
        int g = batch[i];
        atomicAdd(&sAcc[g * 64 + d], v);
        if (d == 0) atomicAdd(&sCnt[g], 1.0f);
    }
    __syncthreads();
    for (int i = tid; i < 4096; i += 256) {
        float v = sAcc[i];
        if (v != 0.0f) atomicAdd(&pooled[i], v);
    }
    if (tid < 64) {
        float v = sCnt[tid];
        if (v != 0.0f) atomicAdd(&cnt[tid], v);
    }
}

// ---------------- out[g,o] = (pooled[g,:]/max(cnt,1)) @ fcw + fcb ----------------
__global__ void final_fc(const float* __restrict__ pooled, const float* __restrict__ cnt,
                         const float* __restrict__ fcw, const float* __restrict__ fcb,
                         float* __restrict__ out) {
    int idx = blockIdx.x * 256 + threadIdx.x;
    if (idx >= 64 * 32) return;
    int g = idx >> 5, o = idx & 31;
    float c = fmaxf(cnt[g], 1.0f);
    float acc = 0.0f;
#pragma unroll
    for (int k = 0; k < 64; ++k) acc = fmaf(pooled[g * 64 + k], fcw[k * 32 + o], acc);
    out[idx] = acc / c + fcb[o];
}

extern "C" void kernel_launch(void* const* d_in, const int* in_sizes, int n_in,
                              void* d_out, int out_size, void* d_ws, size_t ws_size,
                              hipStream_t stream) {
    const float* x       = (const float*)d_in[0];
    const int*   eidx    = (const int*)d_in[1];
    const int*   batch   = (const int*)d_in[2];
    const float* w1_init = (const float*)d_in[3];
    const float* w1_root = (const float*)d_in[4];
    const float* b1      = (const float*)d_in[5];
    const float* w2_init = (const float*)d_in[6];
    const float* w2_root = (const float*)d_in[7];
    const float* b2      = (const float*)d_in[8];
    const float* fc_w    = (const float*)d_in[9];
    const float* fc_b    = (const float*)d_in[10];
    float* out = (float*)d_out;

    const int N = in_sizes[0] / 64;
    const int E = in_sizes[1] / 2;
    const int* row = eidx;
    const int* col = eidx + E;

    const int B = (N + NB - 1) / NB;  // 391 buckets

    // workspace layout (ws 8B-aligned):
    // bpack(B*CAP ull) | es(B*CAP int) | bcnt(B) | nstart(N) | ndeg(N) | dinv(N)
    // | pooled(4096) | cnt(64) | bufA(N*64) | bufB(N*64)
    ull*   bpack  = (ull*)d_ws;
    int*   es     = (int*)(bpack + (size_t)B * CAP);
    int*   bcnt   = es + (size_t)B * CAP;
    int*   nstart = bcnt + B;
    int*   ndeg   = nstart + N;
    float* dinv   = (float*)(ndeg + N);
    float* pooled = dinv + N;
    float* cnt    = pooled + 64 * 64;
    float* bufA   = cnt + 64;
    float* bufB   = bufA + (size_t)N * 64;

    hipMemsetAsync(bcnt, 0, (size_t)B * sizeof(int), stream);
    hipMemsetAsync(pooled, 0, (size_t)(64 * 64 + 64) * sizeof(float), stream);

    // build bucketed CSR + dinv (shared by both layers)
    bucket_kernel<<<(E + P1_CHUNK - 1) / P1_CHUNK, 256, 0, stream>>>(row, col, bpack, bcnt, E);
    csr_kernel<<<B, 256, 0, stream>>>(bpack, bcnt, es, nstart, ndeg, dinv, N);

    // layer 1
    gemm_dual<<<(N + 63) / 64, 256, 0, stream>>>(x, w1_init, w1_root, b1, bufA, bufB, N);
    gather_fused<<<(N + 3) / 4, 256, 0, stream>>>(bufA, bufB, es, nstart, ndeg, dinv, bufB, N);

    // layer 2
    gemm_dual<<<(N + 63) / 64, 256, 0, stream>>>(bufB, w2_init, w2_root, b2, bufA, bufB, N);
    gather_fused<<<(N + 3) / 4, 256, 0, stream>>>(bufA, bufB, es, nstart, ndeg, dinv, bufB, N);

    // pool + FC
    pool_kernel<<<(N + POOL_CHUNK - 1) / POOL_CHUNK, 256, 0, stream>>>(bufB, batch, pooled, cnt, N);
    final_fc<<<(64 * 32 + 255) / 256, 256, 0, stream>>>(pooled, cnt, fc_w, fc_b, out);
}

// Round 6
// 397.728 us; speedup vs baseline: 4.5931x; 1.1593x over previous
//
#include <hip/hip_runtime.h>
#include <hip/hip_bf16.h>

// ARMANet: 2x ARMAConv(K=1,T=1) + global mean pool + FC
// N=100000 nodes, E=1600000 edges, IN=HID=64, OUT=32, G=64 graphs.
// R6: R5 + (a) high-parallelism register-accumulating pool (batch is sorted),
//     (b) dinv[src] folded into GEMM epilogue so gather is shfl+load+add,
//     (c) 8-way unrolled gather inner loop.

#define NB 256          // destination nodes per bucket
#define CAP 5120        // edge capacity per bucket (mean 4092, sigma ~64)
#define MAXB 400        // max buckets (N=100000 -> 391)
#define P1_CHUNK 4096   // edges per bucket_kernel block

typedef unsigned long long ull;

// ---------------- stage 1: bucket edges by destination (block-local multi-split) ----------------
__global__ __launch_bounds__(256) void bucket_kernel(
    const int* __restrict__ row, const int* __restrict__ col,
    ull* __restrict__ bpack, int* __restrict__ bcnt, int E) {
    __shared__ int hist[MAXB];
    __shared__ int ofs[MAXB];
    __shared__ int cur[MAXB];
    __shared__ int gbase[MAXB];
    __shared__ int s[256];
    __shared__ ull stage[P1_CHUNK];

    int t = threadIdx.x;
    for (int i = t; i < MAXB; i += 256) hist[i] = 0;
    __syncthreads();

    int e0 = blockIdx.x * P1_CHUNK;
    int cntE = min(E - e0, P1_CHUNK);

    // ph1: histogram over destination buckets
    for (int i = t; i < cntE; i += 256) {
        int c = col[e0 + i];
        atomicAdd(&hist[c >> 8], 1);
    }
    __syncthreads();

    // ph2: exclusive scan of hist
    int i2 = 2 * t;
    int a = (i2 < MAXB) ? hist[i2] : 0;
    int b = (i2 + 1 < MAXB) ? hist[i2 + 1] : 0;
    s[t] = a + b;
    __syncthreads();
    for (int off = 1; off < 256; off <<= 1) {
        int x = (t >= off) ? s[t - off] : 0;
        __syncthreads();
        s[t] += x;
        __syncthreads();
    }
    int excl = (t > 0) ? s[t - 1] : 0;
    if (i2 < MAXB) ofs[i2] = excl;
    if (i2 + 1 < MAXB) ofs[i2 + 1] = excl + a;
    __syncthreads();

    // reserve global space: one atomic per non-empty bucket per block
    for (int i = t; i < MAXB; i += 256) {
        cur[i] = ofs[i];
        gbase[i] = hist[i] ? atomicAdd(&bcnt[i], hist[i]) : 0;
    }
    __syncthreads();

    // ph3: stage edges grouped by bucket in LDS
    for (int i = t; i < cntE; i += 256) {
        int c = col[e0 + i];
        int r = row[e0 + i];
        int bk = c >> 8;
        int k = atomicAdd(&cur[bk], 1);
        stage[k] = ((ull)(unsigned)c << 32) | (unsigned)r;
    }
    __syncthreads();

    // ph4: contiguous per-bucket runs -> global
    for (int i = t; i < cntE; i += 256) {
        ull pk = stage[i];
        int c = (int)(pk >> 32);
        int bk = c >> 8;
        int gd = gbase[bk] + (i - ofs[bk]);
        if (gd < CAP) bpack[(size_t)bk * CAP + gd] = pk;
    }
}

// ---------------- stage 2: per-bucket counting sort -> CSR + dinv ----------------
__global__ __launch_bounds__(256) void csr_kernel(
    const ull* __restrict__ bpack, const int* __restrict__ bcnt,
    int* __restrict__ es, int* __restrict__ nstart, int* __restrict__ ndeg,
    float* __restrict__ dinv, int n) {
    __shared__ int h[NB];
    __shared__ int s[NB];
    __shared__ int cur[NB];
    int b = blockIdx.x, t = threadIdx.x;
    h[t] = 0;
    __syncthreads();
    int cnt = min(bcnt[b], CAP);
    size_t base = (size_t)b * CAP;
    for (int i = t; i < cnt; i += 256) {
        int c = (int)(bpack[base + i] >> 32);
        atomicAdd(&h[c & (NB - 1)], 1);
    }
    __syncthreads();
    s[t] = h[t];
    __syncthreads();
    for (int off = 1; off < 256; off <<= 1) {
        int x = (t >= off) ? s[t - off] : 0;
        __syncthreads();
        s[t] += x;
        __syncthreads();
    }
    int myofs = s[t] - h[t];  // exclusive
    cur[t] = myofs;
    int node = b * NB + t;
    if (node < n) {
        nstart[node] = (int)base + myofs;
        ndeg[node] = h[t];
        dinv[node] = h[t] ? rsqrtf((float)h[t]) : 0.0f;
    }
    __syncthreads();
    // scatter src ids into this bucket's 20KB window (L2-local)
    for (int i = t; i < cnt; i += 256) {
        ull pk = bpack[base + i];
        int cl = ((int)(pk >> 32)) & (NB - 1);
        int p = atomicAdd(&cur[cl], 1);
        es[base + p] = (int)pk;
    }
}

// ---------------- dual GEMM: T = dinv .* (X@W1), R = X@W2 + b ----------------
__global__ __launch_bounds__(256) void gemm_dual(
    const float* __restrict__ X, const float* __restrict__ W1,
    const float* __restrict__ W2, const float* __restrict__ bias,
    const float* __restrict__ dinv,
    float* __restrict__ T, float* __restrict__ R, int n) {
    __shared__ float sX[64 * 64];
    int t = threadIdx.x;
    int d = t & 63;
    int i0 = t >> 6;

    float w1r[64], w2r[64];
#pragma unroll
    for (int k = 0; k < 64; ++k) {
        w1r[k] = W1[k * 64 + d];
        w2r[k] = W2[k * 64 + d];
    }

    int node0 = blockIdx.x * 64;
    for (int i = t * 4; i < 4096; i += 1024) {
        int rr = i >> 6, cc = i & 63;
        int node = node0 + rr;
        float4 v = make_float4(0.f, 0.f, 0.f, 0.f);
        if (node < n) v = *(const float4*)&X[(size_t)node * 64 + cc];
        *(float4*)&sX[i] = v;
    }
    __syncthreads();

    float bi = bias[d];
    for (int i = i0; i < 64; i += 4) {
        int node = node0 + i;
        if (node >= n) break;
        float a1 = 0.f, a2 = 0.f;
#pragma unroll
        for (int k4 = 0; k4 < 16; ++k4) {
            float4 xv = *(const float4*)&sX[i * 64 + k4 * 4];
            a1 = fmaf(xv.x, w1r[k4 * 4 + 0], a1);
            a2 = fmaf(xv.x, w2r[k4 * 4 + 0], a2);
            a1 = fmaf(xv.y, w1r[k4 * 4 + 1], a1);
            a2 = fmaf(xv.y, w2r[k4 * 4 + 1], a2);
            a1 = fmaf(xv.z, w1r[k4 * 4 + 2], a1);
            a2 = fmaf(xv.z, w2r[k4 * 4 + 2], a2);
            a1 = fmaf(xv.w, w1r[k4 * 4 + 3], a1);
            a2 = fmaf(xv.w, w2r[k4 * 4 + 3], a2);
        }
        T[(size_t)node * 64 + d] = a1 * dinv[node];
        R[(size_t)node * 64 + d] = a2 + bi;
    }
}

// ---------------- fused gather-propagate + relu (one wave per dst node) ----------------
// H[c,:] = relu( dinv[c] * sum_{e in CSR(c)} Ts[src,:] + R[c,:] ), Ts pre-scaled by dinv[src].
__global__ __launch_bounds__(256) void gather_fused(
    const float* __restrict__ Ts, const float* __restrict__ R,
    const int* __restrict__ es, const int* __restrict__ nstart,
    const int* __restrict__ ndeg, const float* __restrict__ dinv,
    float* __restrict__ H, int n) {
    int c = blockIdx.x * 4 + (threadIdx.x >> 6);
    if (c >= n) return;
    int d = threadIdx.x & 63;
    int deg = ndeg[c];
    int s0 = nstart[c];
    float acc = 0.0f;
    for (int base = 0; base < deg; base += 64) {
        int m = min(deg - base, 64);
        int sid = (d < m) ? es[s0 + base + d] : 0;
        int j = 0;
        for (; j + 8 <= m; j += 8) {
            int r0 = __shfl(sid, j),     r1 = __shfl(sid, j + 1);
            int r2 = __shfl(sid, j + 2), r3 = __shfl(sid, j + 3);
            int r4 = __shfl(sid, j + 4), r5 = __shfl(sid, j + 5);
            int r6 = __shfl(sid, j + 6), r7 = __shfl(sid, j + 7);
            float t0 = Ts[(size_t)r0 * 64 + d];
            float t1 = Ts[(size_t)r1 * 64 + d];
            float t2 = Ts[(size_t)r2 * 64 + d];
            float t3 = Ts[(size_t)r3 * 64 + d];
            float t4 = Ts[(size_t)r4 * 64 + d];
            float t5 = Ts[(size_t)r5 * 64 + d];
            float t6 = Ts[(size_t)r6 * 64 + d];
            float t7 = Ts[(size_t)r7 * 64 + d];
            acc += t0 + t1 + t2 + t3 + t4 + t5 + t6 + t7;
        }
        for (; j < m; ++j) {
            int r0 = __shfl(sid, j);
            acc += Ts[(size_t)r0 * 64 + d];
        }
    }
    float hv = fmaf(dinv[c], acc, R[(size_t)c * 64 + d]);
    H[(size_t)c * 64 + d] = fmaxf(hv, 0.0f);
}

// ---------------- mean-pool: batch is SORTED -> register accumulate per wave ----------------
__global__ __launch_bounds__(256) void pool_kernel(
    const float* __restrict__ Hin, const int* __restrict__ batch,
    float* __restrict__ pooled, float* __restrict__ cnt, int n) {
    __shared__ float sAcc[64 * 64];
    __shared__ float sCnt[64];
    int tid = threadIdx.x;
    for (int i = tid; i < 4096; i += 256) sAcc[i] = 0.0f;
    if (tid < 64) sCnt[tid] = 0.0f;
    __syncthreads();

    int w = tid >> 6, d = tid & 63;
    int s = blockIdx.x * 256 + w * 64;   // this wave's 64 consecutive nodes
    int e = min(s + 64, n);
    float acc = 0.0f, c = 0.0f;
    int gcur = -1;
    for (int i = s; i < e; ++i) {
        int g = batch[i];                 // wave-uniform (sorted, broadcast)
        if (g != gcur) {                  // rare, wave-uniform branch
            if (gcur >= 0) {
                atomicAdd(&sAcc[gcur * 64 + d], acc);
                if (d == 0) atomicAdd(&sCnt[gcur], c);
            }
            gcur = g; acc = 0.0f; c = 0.0f;
        }
        acc += Hin[(size_t)i * 64 + d];
        c += 1.0f;
    }
    if (gcur >= 0) {
        atomicAdd(&sAcc[gcur * 64 + d], acc);
        if (d == 0) atomicAdd(&sCnt[gcur], c);
    }
    __syncthreads();
    for (int i = tid; i < 4096; i += 256) {
        float v = sAcc[i];
        if (v != 0.0f) atomicAdd(&pooled[i], v);
    }
    if (tid < 64) {
        float v = sCnt[tid];
        if (v != 0.0f) atomicAdd(&cnt[tid], v);
    }
}

// ---------------- out[g,o] = (pooled[g,:]/max(cnt,1)) @ fcw + fcb ----------------
__global__ void final_fc(const float* __restrict__ pooled, const float* __restrict__ cnt,
                         const float* __restrict__ fcw, const float* __restrict__ fcb,
                         float* __restrict__ out) {
    int idx = blockIdx.x * 256 + threadIdx.x;
    if (idx >= 64 * 32) return;
    int g = idx >> 5, o = idx & 31;
    float c = fmaxf(cnt[g], 1.0f);
    float acc = 0.0f;
#pragma unroll
    for (int k = 0; k < 64; ++k) acc = fmaf(pooled[g * 64 + k], fcw[k * 32 + o], acc);
    out[idx] = acc / c + fcb[o];
}

extern "C" void kernel_launch(void* const* d_in, const int* in_sizes, int n_in,
                              void* d_out, int out_size, void* d_ws, size_t ws_size,
                              hipStream_t stream) {
    const float* x       = (const float*)d_in[0];
    const int*   eidx    = (const int*)d_in[1];
    const int*   batch   = (const int*)d_in[2];
    const float* w1_init = (const float*)d_in[3];
    const float* w1_root = (const float*)d_in[4];
    const float* b1      = (const float*)d_in[5];
    const float* w2_init = (const float*)d_in[6];
    const float* w2_root = (const float*)d_in[7];
    const float* b2      = (const float*)d_in[8];
    const float* fc_w    = (const float*)d_in[9];
    const float* fc_b    = (const float*)d_in[10];
    float* out = (float*)d_out;

    const int N = in_sizes[0] / 64;
    const int E = in_sizes[1] / 2;
    const int* row = eidx;
    const int* col = eidx + E;

    const int B = (N + NB - 1) / NB;  // 391 buckets

    // workspace layout (ws 8B-aligned):
    // bpack(B*CAP ull) | es(B*CAP int) | bcnt(B) | nstart(N) | ndeg(N) | dinv(N)
    // | pooled(4096) | cnt(64) | bufA(N*64) | bufB(N*64)
    ull*   bpack  = (ull*)d_ws;
    int*   es     = (int*)(bpack + (size_t)B * CAP);
    int*   bcnt   = es + (size_t)B * CAP;
    int*   nstart = bcnt + B;
    int*   ndeg   = nstart + N;
    float* dinv   = (float*)(ndeg + N);
    float* pooled = dinv + N;
    float* cnt    = pooled + 64 * 64;
    float* bufA   = cnt + 64;
    float* bufB   = bufA + (size_t)N * 64;

    hipMemsetAsync(bcnt, 0, (size_t)B * sizeof(int), stream);
    hipMemsetAsync(pooled, 0, (size_t)(64 * 64 + 64) * sizeof(float), stream);

    // build bucketed CSR + dinv (shared by both layers)
    bucket_kernel<<<(E + P1_CHUNK - 1) / P1_CHUNK, 256, 0, stream>>>(row, col, bpack, bcnt, E);
    csr_kernel<<<B, 256, 0, stream>>>(bpack, bcnt, es, nstart, ndeg, dinv, N);

    // layer 1
    gemm_dual<<<(N + 63) / 64, 256, 0, stream>>>(x, w1_init, w1_root, b1, dinv, bufA, bufB, N);
    gather_fused<<<(N + 3) / 4, 256, 0, stream>>>(bufA, bufB, es, nstart, ndeg, dinv, bufB, N);

    // layer 2
    gemm_dual<<<(N + 63) / 64, 256, 0, stream>>>(bufB, w2_init, w2_root, b2, dinv, bufA, bufB, N);
    gather_fused<<<(N + 3) / 4, 256, 0, stream>>>(bufA, bufB, es, nstart, ndeg, dinv, bufB, N);

    // pool + FC
    pool_kernel<<<(N + 255) / 256, 256, 0, stream>>>(bufB, batch, pooled, cnt, N);
    final_fc<<<(64 * 32 + 255) / 256, 256, 0, stream>>>(pooled, cnt, fc_w, fc_b, out);
}

// Round 7
// 375.059 us; speedup vs baseline: 4.8707x; 1.0604x over previous
//
#include <hip/hip_runtime.h>
#include <hip/hip_bf16.h>

// ARMANet: 2x ARMAConv(K=1,T=1) + global mean pool + FC
// N=100000 nodes, E=1600000 edges, IN=HID=64, OUT=32, G=64 graphs.
// R7: R6 + (a) bf16 gather payload Ts (halves the dominant scattered-read
//     traffic), (b) gemm_dual restructured: one W column per thread
//     (512 thr: 64 dims x {T,R} x 4 node-quarters) for ~2x occupancy.

#define NB 256          // destination nodes per bucket
#define CAP 5120        // edge capacity per bucket (mean 4092, sigma ~64)
#define MAXB 400        // max buckets (N=100000 -> 391)
#define P1_CHUNK 4096   // edges per bucket_kernel block

typedef unsigned long long ull;

// ---------------- stage 1: bucket edges by destination (block-local multi-split) ----------------
__global__ __launch_bounds__(256) void bucket_kernel(
    const int* __restrict__ row, const int* __restrict__ col,
    ull* __restrict__ bpack, int* __restrict__ bcnt, int E) {
    __shared__ int hist[MAXB];
    __shared__ int ofs[MAXB];
    __shared__ int cur[MAXB];
    __shared__ int gbase[MAXB];
    __shared__ int s[256];
    __shared__ ull stage[P1_CHUNK];

    int t = threadIdx.x;
    for (int i = t; i < MAXB; i += 256) hist[i] = 0;
    __syncthreads();

    int e0 = blockIdx.x * P1_CHUNK;
    int cntE = min(E - e0, P1_CHUNK);

    // ph1: histogram over destination buckets
    for (int i = t; i < cntE; i += 256) {
        int c = col[e0 + i];
        atomicAdd(&hist[c >> 8], 1);
    }
    __syncthreads();

    // ph2: exclusive scan of hist
    int i2 = 2 * t;
    int a = (i2 < MAXB) ? hist[i2] : 0;
    int b = (i2 + 1 < MAXB) ? hist[i2 + 1] : 0;
    s[t] = a + b;
    __syncthreads();
    for (int off = 1; off < 256; off <<= 1) {
        int x = (t >= off) ? s[t - off] : 0;
        __syncthreads();
        s[t] += x;
        __syncthreads();
    }
    int excl = (t > 0) ? s[t - 1] : 0;
    if (i2 < MAXB) ofs[i2] = excl;
    if (i2 + 1 < MAXB) ofs[i2 + 1] = excl + a;
    __syncthreads();

    // reserve global space: one atomic per non-empty bucket per block
    for (int i = t; i < MAXB; i += 256) {
        cur[i] = ofs[i];
        gbase[i] = hist[i] ? atomicAdd(&bcnt[i], hist[i]) : 0;
    }
    __syncthreads();

    // ph3: stage edges grouped by bucket in LDS
    for (int i = t; i < cntE; i += 256) {
        int c = col[e0 + i];
        int r = row[e0 + i];
        int bk = c >> 8;
        int k = atomicAdd(&cur[bk], 1);
        stage[k] = ((ull)(unsigned)c << 32) | (unsigned)r;
    }
    __syncthreads();

    // ph4: contiguous per-bucket runs -> global
    for (int i = t; i < cntE; i += 256) {
        ull pk = stage[i];
        int c = (int)(pk >> 32);
        int bk = c >> 8;
        int gd = gbase[bk] + (i - ofs[bk]);
        if (gd < CAP) bpack[(size_t)bk * CAP + gd] = pk;
    }
}

// ---------------- stage 2: per-bucket counting sort -> CSR + dinv ----------------
__global__ __launch_bounds__(256) void csr_kernel(
    const ull* __restrict__ bpack, const int* __restrict__ bcnt,
    int* __restrict__ es, int* __restrict__ nstart, int* __restrict__ ndeg,
    float* __restrict__ dinv, int n) {
    __shared__ int h[NB];
    __shared__ int s[NB];
    __shared__ int cur[NB];
    int b = blockIdx.x, t = threadIdx.x;
    h[t] = 0;
    __syncthreads();
    int cnt = min(bcnt[b], CAP);
    size_t base = (size_t)b * CAP;
    for (int i = t; i < cnt; i += 256) {
        int c = (int)(bpack[base + i] >> 32);
        atomicAdd(&h[c & (NB - 1)], 1);
    }
    __syncthreads();
    s[t] = h[t];
    __syncthreads();
    for (int off = 1; off < 256; off <<= 1) {
        int x = (t >= off) ? s[t - off] : 0;
        __syncthreads();
        s[t] += x;
        __syncthreads();
    }
    int myofs = s[t] - h[t];  // exclusive
    cur[t] = myofs;
    int node = b * NB + t;
    if (node < n) {
        nstart[node] = (int)base + myofs;
        ndeg[node] = h[t];
        dinv[node] = h[t] ? rsqrtf((float)h[t]) : 0.0f;
    }
    __syncthreads();
    // scatter src ids into this bucket's 20KB window (L2-local)
    for (int i = t; i < cnt; i += 256) {
        ull pk = bpack[base + i];
        int cl = ((int)(pk >> 32)) & (NB - 1);
        int p = atomicAdd(&cur[cl], 1);
        es[base + p] = (int)pk;
    }
}

// ---------------- dual GEMM: Ts = bf16(dinv .* (X@W1)), R = X@W2 + b ----------------
// 512 threads: d = dim (64), sel = which output (2), q = node quarter (4).
__global__ __launch_bounds__(512) void gemm_dual(
    const float* __restrict__ X, const float* __restrict__ W1,
    const float* __restrict__ W2, const float* __restrict__ bias,
    const float* __restrict__ dinv,
    __hip_bfloat16* __restrict__ Ts, float* __restrict__ R, int n) {
    __shared__ float sX[64 * 64];
    int t = threadIdx.x;
    int d = t & 63;
    int sel = (t >> 6) & 1;
    int q = t >> 7;  // 0..3

    const float* __restrict__ W = sel ? W2 : W1;
    float wr[64];
#pragma unroll
    for (int k = 0; k < 64; ++k) wr[k] = W[k * 64 + d];

    int node0 = blockIdx.x * 64;
    for (int i = t * 4; i < 4096; i += 2048) {
        int rr = i >> 6, cc = i & 63;
        int node = node0 + rr;
        float4 v = make_float4(0.f, 0.f, 0.f, 0.f);
        if (node < n) v = *(const float4*)&X[(size_t)node * 64 + cc];
        *(float4*)&sX[i] = v;
    }
    __syncthreads();

    float bi = bias[d];
    for (int i = q; i < 64; i += 4) {
        int node = node0 + i;
        if (node >= n) break;
        float acc = 0.f;
#pragma unroll
        for (int k4 = 0; k4 < 16; ++k4) {
            float4 xv = *(const float4*)&sX[i * 64 + k4 * 4];
            acc = fmaf(xv.x, wr[k4 * 4 + 0], acc);
            acc = fmaf(xv.y, wr[k4 * 4 + 1], acc);
            acc = fmaf(xv.z, wr[k4 * 4 + 2], acc);
            acc = fmaf(xv.w, wr[k4 * 4 + 3], acc);
        }
        if (sel == 0) {
            Ts[(size_t)node * 64 + d] = __float2bfloat16(acc * dinv[node]);
        } else {
            R[(size_t)node * 64 + d] = acc + bi;
        }
    }
}

// ---------------- fused gather-propagate + relu (one wave per dst node) ----------------
// H[c,:] = relu( dinv[c] * sum_{e in CSR(c)} Ts[src,:] + R[c,:] ), Ts pre-scaled by dinv[src].
__global__ __launch_bounds__(256) void gather_fused(
    const __hip_bfloat16* __restrict__ Ts, const float* __restrict__ R,
    const int* __restrict__ es, const int* __restrict__ nstart,
    const int* __restrict__ ndeg, const float* __restrict__ dinv,
    float* __restrict__ H, int n) {
    int c = blockIdx.x * 4 + (threadIdx.x >> 6);
    if (c >= n) return;
    int d = threadIdx.x & 63;
    int deg = ndeg[c];
    int s0 = nstart[c];
    float acc = 0.0f;
    for (int base = 0; base < deg; base += 64) {
        int m = min(deg - base, 64);
        int sid = (d < m) ? es[s0 + base + d] : 0;
        int j = 0;
        for (; j + 8 <= m; j += 8) {
            int r0 = __shfl(sid, j),     r1 = __shfl(sid, j + 1);
            int r2 = __shfl(sid, j + 2), r3 = __shfl(sid, j + 3);
            int r4 = __shfl(sid, j + 4), r5 = __shfl(sid, j + 5);
            int r6 = __shfl(sid, j + 6), r7 = __shfl(sid, j + 7);
            float t0 = __bfloat162float(Ts[(size_t)r0 * 64 + d]);
            float t1 = __bfloat162float(Ts[(size_t)r1 * 64 + d]);
            float t2 = __bfloat162float(Ts[(size_t)r2 * 64 + d]);
            float t3 = __bfloat162float(Ts[(size_t)r3 * 64 + d]);
            float t4 = __bfloat162float(Ts[(size_t)r4 * 64 + d]);
            float t5 = __bfloat162float(Ts[(size_t)r5 * 64 + d]);
            float t6 = __bfloat162float(Ts[(size_t)r6 * 64 + d]);
            float t7 = __bfloat162float(Ts[(size_t)r7 * 64 + d]);
            acc += ((t0 + t1) + (t2 + t3)) + ((t4 + t5) + (t6 + t7));
        }
        for (; j < m; ++j) {
            int r0 = __shfl(sid, j);
            acc += __bfloat162float(Ts[(size_t)r0 * 64 + d]);
        }
    }
    float hv = fmaf(dinv[c], acc, R[(size_t)c * 64 + d]);
    H[(size_t)c * 64 + d] = fmaxf(hv, 0.0f);
}

// ---------------- mean-pool: batch is SORTED -> register accumulate per wave ----------------
__global__ __launch_bounds__(256) void pool_kernel(
    const float* __restrict__ Hin, const int* __restrict__ batch,
    float* __restrict__ pooled, float* __restrict__ cnt, int n) {
    __shared__ float sAcc[64 * 64];
    __shared__ float sCnt[64];
    int tid = threadIdx.x;
    for (int i = tid; i < 4096; i += 256) sAcc[i] = 0.0f;
    if (tid < 64) sCnt[tid] = 0.0f;
    __syncthreads();

    int w = tid >> 6, d = tid & 63;
    int s = blockIdx.x * 256 + w * 64;   // this wave's 64 consecutive nodes
    int e = min(s + 64, n);
    float acc = 0.0f, c = 0.0f;
    int gcur = -1;
    for (int i = s; i < e; ++i) {
        int g = batch[i];                 // wave-uniform (sorted, broadcast)
        if (g != gcur) {                  // rare, wave-uniform branch
            if (gcur >= 0) {
                atomicAdd(&sAcc[gcur * 64 + d], acc);
                if (d == 0) atomicAdd(&sCnt[gcur], c);
            }
            gcur = g; acc = 0.0f; c = 0.0f;
        }
        acc += Hin[(size_t)i * 64 + d];
        c += 1.0f;
    }
    if (gcur >= 0) {
        atomicAdd(&sAcc[gcur * 64 + d], acc);
        if (d == 0) atomicAdd(&sCnt[gcur], c);
    }
    __syncthreads();
    for (int i = tid; i < 4096; i += 256) {
        float v = sAcc[i];
        if (v != 0.0f) atomicAdd(&pooled[i], v);
    }
    if (tid < 64) {
        float v = sCnt[tid];
        if (v != 0.0f) atomicAdd(&cnt[tid], v);
    }
}

// ---------------- out[g,o] = (pooled[g,:]/max(cnt,1)) @ fcw + fcb ----------------
__global__ void final_fc(const float* __restrict__ pooled, const float* __restrict__ cnt,
                         const float* __restrict__ fcw, const float* __restrict__ fcb,
                         float* __restrict__ out) {
    int idx = blockIdx.x * 256 + threadIdx.x;
    if (idx >= 64 * 32) return;
    int g = idx >> 5, o = idx & 31;
    float c = fmaxf(cnt[g], 1.0f);
    float acc = 0.0f;
#pragma unroll
    for (int k = 0; k < 64; ++k) acc = fmaf(pooled[g * 64 + k], fcw[k * 32 + o], acc);
    out[idx] = acc / c + fcb[o];
}

extern "C" void kernel_launch(void* const* d_in, const int* in_sizes, int n_in,
                              void* d_out, int out_size, void* d_ws, size_t ws_size,
                              hipStream_t stream) {
    const float* x       = (const float*)d_in[0];
    const int*   eidx    = (const int*)d_in[1];
    const int*   batch   = (const int*)d_in[2];
    const float* w1_init = (const float*)d_in[3];
    const float* w1_root = (const float*)d_in[4];
    const float* b1      = (const float*)d_in[5];
    const float* w2_init = (const float*)d_in[6];
    const float* w2_root = (const float*)d_in[7];
    const float* b2      = (const float*)d_in[8];
    const float* fc_w    = (const float*)d_in[9];
    const float* fc_b    = (const float*)d_in[10];
    float* out = (float*)d_out;

    const int N = in_sizes[0] / 64;
    const int E = in_sizes[1] / 2;
    const int* row = eidx;
    const int* col = eidx + E;

    const int B = (N + NB - 1) / NB;  // 391 buckets

    // workspace layout (ws 8B-aligned):
    // bpack(B*CAP ull) | es(B*CAP int) | bcnt(B) | nstart(N) | ndeg(N) | dinv(N)
    // | pooled(4096) | cnt(64) | bufA(N*64 float; used as bf16 Ts) | bufB(N*64 float)
    ull*   bpack  = (ull*)d_ws;
    int*   es     = (int*)(bpack + (size_t)B * CAP);
    int*   bcnt   = es + (size_t)B * CAP;
    int*   nstart = bcnt + B;
    int*   ndeg   = nstart + N;
    float* dinv   = (float*)(ndeg + N);
    float* pooled = dinv + N;
    float* cnt    = pooled + 64 * 64;
    float* bufA   = cnt + 64;
    float* bufB   = bufA + (size_t)N * 64;
    __hip_bfloat16* Ts = (__hip_bfloat16*)bufA;

    hipMemsetAsync(bcnt, 0, (size_t)B * sizeof(int), stream);
    hipMemsetAsync(pooled, 0, (size_t)(64 * 64 + 64) * sizeof(float), stream);

    // build bucketed CSR + dinv (shared by both layers)
    bucket_kernel<<<(E + P1_CHUNK - 1) / P1_CHUNK, 256, 0, stream>>>(row, col, bpack, bcnt, E);
    csr_kernel<<<B, 256, 0, stream>>>(bpack, bcnt, es, nstart, ndeg, dinv, N);

    // layer 1
    gemm_dual<<<(N + 63) / 64, 512, 0, stream>>>(x, w1_init, w1_root, b1, dinv, Ts, bufB, N);
    gather_fused<<<(N + 3) / 4, 256, 0, stream>>>(Ts, bufB, es, nstart, ndeg, dinv, bufB, N);

    // layer 2
    gemm_dual<<<(N + 63) / 64, 512, 0, stream>>>(bufB, w2_init, w2_root, b2, dinv, Ts, bufB, N);
    gather_fused<<<(N + 3) / 4, 256, 0, stream>>>(Ts, bufB, es, nstart, ndeg, dinv, bufB, N);

    // pool + FC
    pool_kernel<<<(N + 255) / 256, 256, 0, stream>>>(bufB, batch, pooled, cnt, N);
    final_fc<<<(64 * 32 + 255) / 256, 256, 0, stream>>>(pooled, cnt, fc_w, fc_b, out);
}